// Round 12
// baseline (121.794 us; speedup 1.0000x reference)
//
#include <hip/hip_runtime.h>

#define NN 50000
#define NE 640000
#define CH 128
#define CAP 64                          // slots per node; P(deg>=64)~e^-61 for Poisson(12.8)
#define FILL_BLKS ((NE + 255) / 256)    // 2500
#define CONV_BLKS (NN * CH / 4 / 256)   // 6250

typedef __attribute__((ext_vector_type(8))) short bf16x8;
typedef __attribute__((ext_vector_type(4))) float f32x4;

// f32 -> bf16 (RNE)
__device__ __forceinline__ unsigned short f2bf(float x) {
    unsigned int b = __float_as_uint(x);
    b += 0x7fffu + ((b >> 16) & 1u);
    return (unsigned short)(b >> 16);
}
// bf16 pair (packed in uint) -> f32, free bit-ops
__device__ __forceinline__ float bflo(unsigned int u) { return __uint_as_float(u << 16); }
__device__ __forceinline__ float bfhi(unsigned int u) { return __uint_as_float(u & 0xffff0000u); }

// ---- prep: zero cnt (blocks 0..48) + pack W1,W2 to MFMA frag layout (blocks 49..64) ----
__global__ __launch_bounds__(256) void prep(uint4* __restrict__ cntz,
                                            const float* __restrict__ W1,
                                            const float* __restrict__ W2,
                                            unsigned short* __restrict__ Wp) {
    int b = blockIdx.x;
    if (b < 49) {
        int i = b * 256 + threadIdx.x;          // cnt = 50000 ints = 12500 uint4
        if (i < 12500) cntz[i] = make_uint4(0u, 0u, 0u, 0u);
        return;
    }
    int gid = (b - 49) * 256 + threadIdx.x;     // [0, 4096)
    if (gid >= 4096) return;
    const float* W = (gid < 2048) ? W1 : W2;
    int g = gid & 2047;
    int f = g >> 6, l = g & 63;
    int ct = f >> 2, kb = f & 3;
    int col = ct * 16 + (l & 15);
    int k0 = kb * 32 + (l >> 4) * 8;
    unsigned short t[8];
#pragma unroll
    for (int i = 0; i < 8; ++i) t[i] = f2bf(W[(k0 + i) * CH + col]);
    uint4 v;
    v.x = (unsigned)t[0] | ((unsigned)t[1] << 16);
    v.y = (unsigned)t[2] | ((unsigned)t[3] << 16);
    v.z = (unsigned)t[4] | ((unsigned)t[5] << 16);
    v.w = (unsigned)t[6] | ((unsigned)t[7] << 16);
    ((uint4*)Wp)[gid] = v;
}

// ---- split grid: bin edges (blocks [0,FILL)) + convert v0->bf16 (rest); no LDS ----
__global__ __launch_bounds__(256) void fill_conv(const int* __restrict__ srcIdx,
                                                 const int* __restrict__ dstIdx,
                                                 int* __restrict__ cnt,
                                                 unsigned short* __restrict__ slots,
                                                 const float* __restrict__ v0,
                                                 unsigned short* __restrict__ Xb0) {
    int b = blockIdx.x;
    if (b < FILL_BLKS) {
        int e = b * 256 + threadIdx.x;
        if (e < NE) {
            int d = dstIdx[e];
            int p = atomicAdd(&cnt[d], 1);
            if (p < CAP) slots[(size_t)d * CAP + p] = (unsigned short)srcIdx[e];
        }
        return;
    }
    int i = (b - FILL_BLKS) * 256 + threadIdx.x;   // [0, NN*CH/4)
    float4 v = ((const float4*)v0)[i];
    uint2 o;
    o.x = (unsigned)f2bf(v.x) | ((unsigned)f2bf(v.y) << 16);
    o.y = (unsigned)f2bf(v.z) | ((unsigned)f2bf(v.w) << 16);
    ((uint2*)Xb0)[i] = o;
}

// ---- fused layer: Y = (agg X) @ W + b (+relu) ----
// Phase A: 16 groups x 16 lanes; group g gathers nodes base+4g..4g+3,
//          16 edges in flight; writes bf16 agg rows into XOR-swizzled LDS.
// Phase B: 4 waves x 16 rows MFMA; W fragments read straight from global (L2-bcast);
//          epilogue adds bias[col], optional relu, stores bf16 or f32.
template <int RELU, int F32OUT>
__global__ __launch_bounds__(256) void ggemm(const uint4* __restrict__ H128,
                                             const int* __restrict__ cnt,
                                             const unsigned short* __restrict__ slots,
                                             const float* __restrict__ bias,
                                             const unsigned short* __restrict__ Wp,
                                             unsigned short* __restrict__ Ybf,
                                             float* __restrict__ Yf32) {
    __shared__ unsigned short Xl[64 * 128];      // 16 KiB agg-tile, XOR-swizzled rows
    int tid = threadIdx.x;
    int g = tid >> 4, t = tid & 15;
    int base = blockIdx.x * 64;

    for (int j = 0; j < 4; ++j) {
        int nl = g * 4 + j;
        int node = base + nl;
        float acc[8];
#pragma unroll
        for (int k = 0; k < 8; ++k) acc[k] = 0.f;
        if (node < NN) {
            int d = min(cnt[node], CAP);
            const unsigned short* sl = slots + (size_t)node * CAP;
            int last = d - 1;
            for (int i = 0; i < d; i += 16) {
                int e[16];
                uint4 v[16];
                float m[16];
#pragma unroll
                for (int k = 0; k < 16; ++k) e[k] = sl[min(i + k, last)];
#pragma unroll
                for (int k = 0; k < 16; ++k) v[k] = H128[(size_t)e[k] * 16 + t];
#pragma unroll
                for (int k = 0; k < 16; ++k) m[k] = (i + k <= last) ? 1.f : 0.f;
#pragma unroll
                for (int k = 0; k < 16; ++k) {
                    acc[0] = fmaf(m[k], bflo(v[k].x), acc[0]);
                    acc[1] = fmaf(m[k], bfhi(v[k].x), acc[1]);
                    acc[2] = fmaf(m[k], bflo(v[k].y), acc[2]);
                    acc[3] = fmaf(m[k], bfhi(v[k].y), acc[3]);
                    acc[4] = fmaf(m[k], bflo(v[k].z), acc[4]);
                    acc[5] = fmaf(m[k], bfhi(v[k].z), acc[5]);
                    acc[6] = fmaf(m[k], bflo(v[k].w), acc[6]);
                    acc[7] = fmaf(m[k], bfhi(v[k].w), acc[7]);
                }
            }
        }
        uint4 o;
        o.x = (unsigned)f2bf(acc[0]) | ((unsigned)f2bf(acc[1]) << 16);
        o.y = (unsigned)f2bf(acc[2]) | ((unsigned)f2bf(acc[3]) << 16);
        o.z = (unsigned)f2bf(acc[4]) | ((unsigned)f2bf(acc[5]) << 16);
        o.w = (unsigned)f2bf(acc[6]) | ((unsigned)f2bf(acc[7]) << 16);
        // XOR-swizzle: 16B chunk index (t) xor'd with row&7
        *(uint4*)&Xl[nl * 128 + ((t * 8) ^ ((nl & 7) << 3))] = o;
    }
    __syncthreads();

    // Phase B: Y = aggX @ W + b (+relu); W from global (L2 broadcast)
    int w = tid >> 6, l = tid & 63;
    int rowl = w * 16 + (l & 15);
    int kq = l >> 4;
    bf16x8 xf[4];
#pragma unroll
    for (int kb = 0; kb < 4; ++kb)
        xf[kb] = *(const bf16x8*)&Xl[rowl * 128 + ((kb * 32 + kq * 8) ^ ((rowl & 7) << 3))];

    f32x4 acq[8];
#pragma unroll
    for (int ct = 0; ct < 8; ++ct) acq[ct] = (f32x4){0.f, 0.f, 0.f, 0.f};
#pragma unroll 2
    for (int ct = 0; ct < 8; ++ct)
#pragma unroll
        for (int kb = 0; kb < 4; ++kb) {
            bf16x8 wf = *(const bf16x8*)&Wp[((ct * 4 + kb) * 64 + l) * 8];
            acq[ct] = __builtin_amdgcn_mfma_f32_16x16x32_bf16(wf, xf[kb], acq[ct], 0, 0, 0);
        }

    int row = base + rowl;
    if (row < NN) {
#pragma unroll
        for (int ct = 0; ct < 8; ++ct) {
            int col = ct * 16 + kq * 4;
            float4 bv = *(const float4*)&bias[col];
            float y0 = acq[ct][0] + bv.x;
            float y1 = acq[ct][1] + bv.y;
            float y2 = acq[ct][2] + bv.z;
            float y3 = acq[ct][3] + bv.w;
            if (RELU) {
                y0 = fmaxf(y0, 0.f); y1 = fmaxf(y1, 0.f);
                y2 = fmaxf(y2, 0.f); y3 = fmaxf(y3, 0.f);
            }
            if (F32OUT) {
                *(float4*)&Yf32[(size_t)row * CH + col] = make_float4(y0, y1, y2, y3);
            } else {
                uint2 o;
                o.x = (unsigned)f2bf(y0) | ((unsigned)f2bf(y1) << 16);
                o.y = (unsigned)f2bf(y2) | ((unsigned)f2bf(y3) << 16);
                *(uint2*)(Ybf + (size_t)row * CH + col) = o;
            }
        }
    }
}

extern "C" void kernel_launch(void* const* d_in, const int* in_sizes, int n_in,
                              void* d_out, int out_size, void* d_ws, size_t ws_size,
                              hipStream_t stream) {
    const float* v0 = (const float*)d_in[0];
    const int* edge = (const int*)d_in[1];   // [2, NE]: row0 = src, row1 = dst
    const float* W1 = (const float*)d_in[2];
    const float* b1 = (const float*)d_in[3];
    const float* W2 = (const float*)d_in[4];
    const float* b2 = (const float*)d_in[5];
    float* out = (float*)d_out;

    const int* srcIdx = edge;
    const int* dstIdx = edge + NE;

    // workspace layout
    unsigned short* Xb0   = (unsigned short*)d_ws;    // [NN*CH] bf16 v0
    unsigned short* Xb1   = Xb0 + (size_t)NN * CH;    // [NN*CH] bf16 layer-1 output x
    unsigned short* Wp    = Xb1 + (size_t)NN * CH;    // [2*16384] packed W1,W2
    int* cnt              = (int*)(Wp + 2 * 16384);   // [NN]
    unsigned short* slots = (unsigned short*)(cnt + NN); // [NN*CAP] ushort src ids

    // K0: zero degree counters + pack weights
    prep<<<65, 256, 0, stream>>>((uint4*)cnt, W1, W2, Wp);

    // K1: bin edges || convert v0 -> bf16 (both LDS-free, full occupancy)
    fill_conv<<<FILL_BLKS + CONV_BLKS, 256, 0, stream>>>(srcIdx, dstIdx, cnt, slots,
                                                         v0, Xb0);

    // K2: layer 1: x = relu((A v0b) @ W1 + b1)   [A(XW) == (AX)W]
    ggemm<1, 0><<<(NN + 63) / 64, 256, 0, stream>>>((const uint4*)Xb0, cnt, slots,
                                                    b1, Wp, Xb1, nullptr);

    // K3: layer 2: out = (A x) @ W2 + b2  (f32 straight from MFMA accumulator)
    ggemm<0, 1><<<(NN + 63) / 64, 256, 0, stream>>>((const uint4*)Xb1, cnt, slots,
                                                    b2, Wp + 16384, nullptr, out);
}

// Round 13
// 118.075 us; speedup vs baseline: 1.0315x; 1.0315x over previous
//
#include <hip/hip_runtime.h>

#define NN 50000
#define NE 640000
#define CH 128
#define CAP 64                          // slots per node; P(deg>=64)~e^-61 for Poisson(12.8)
#define G1B ((NN + 63) / 64)            // 782 gemm1 blocks
#define FILLB ((NE + 255) / 256)        // 2500 fill blocks
#define XPAD 136                        // LDS x-tile pitch (ushorts)

typedef __attribute__((ext_vector_type(8))) short bf16x8;
typedef __attribute__((ext_vector_type(4))) float f32x4;

// f32 -> bf16 (RNE)
__device__ __forceinline__ unsigned short f2bf(float x) {
    unsigned int b = __float_as_uint(x);
    b += 0x7fffu + ((b >> 16) & 1u);
    return (unsigned short)(b >> 16);
}
// bf16 pair (packed in uint) -> f32, free bit-ops
__device__ __forceinline__ float bflo(unsigned int u) { return __uint_as_float(u << 16); }
__device__ __forceinline__ float bfhi(unsigned int u) { return __uint_as_float(u & 0xffff0000u); }

// ---- prep: zero cnt (blocks 0..48) + pack W1,W2 to MFMA frag layout (blocks 49..64) ----
__global__ __launch_bounds__(256) void prep(uint4* __restrict__ cntz,
                                            const float* __restrict__ W1,
                                            const float* __restrict__ W2,
                                            unsigned short* __restrict__ Wp) {
    int b = blockIdx.x;
    if (b < 49) {
        int i = b * 256 + threadIdx.x;          // cnt = 50000 ints = 12500 uint4
        if (i < 12500) cntz[i] = make_uint4(0u, 0u, 0u, 0u);
        return;
    }
    int gid = (b - 49) * 256 + threadIdx.x;     // [0, 4096)
    if (gid >= 4096) return;
    const float* W = (gid < 2048) ? W1 : W2;
    int g = gid & 2047;
    int f = g >> 6, l = g & 63;
    int ct = f >> 2, kb = f & 3;
    int col = ct * 16 + (l & 15);
    int k0 = kb * 32 + (l >> 4) * 8;
    unsigned short t[8];
#pragma unroll
    for (int i = 0; i < 8; ++i) t[i] = f2bf(W[(k0 + i) * CH + col]);
    uint4 v;
    v.x = (unsigned)t[0] | ((unsigned)t[1] << 16);
    v.y = (unsigned)t[2] | ((unsigned)t[3] << 16);
    v.z = (unsigned)t[4] | ((unsigned)t[5] << 16);
    v.w = (unsigned)t[6] | ((unsigned)t[7] << 16);
    ((uint4*)Wp)[gid] = v;
}

// ---- split grid, NO LDS anywhere: blocks [0,G1B) h1 = v0 @ W1; rest bin edges ----
__global__ __launch_bounds__(256) void fill_gemm1(const float* __restrict__ v0,
                                                  const unsigned short* __restrict__ Wp,
                                                  unsigned short* __restrict__ Hb,
                                                  const int* __restrict__ srcIdx,
                                                  const int* __restrict__ dstIdx,
                                                  int* __restrict__ cnt,
                                                  unsigned short* __restrict__ slots) {
    int b = blockIdx.x, tid = threadIdx.x;
    if (b >= G1B) {
        int e = (b - G1B) * 256 + tid;
        if (e < NE) {
            int dd = dstIdx[e];
            int p = atomicAdd(&cnt[dd], 1);
            if (p < CAP) slots[(size_t)dd * CAP + p] = (unsigned short)srcIdx[e];
        }
        return;
    }
    // gemm1: rows b*64..+63; W fragments straight from global (L2-resident 32KB)
    int w = tid >> 6, l = tid & 63;
    int row = b * 64 + w * 16 + (l & 15);
    int rc = min(row, NN - 1);
    int kq = l >> 4;

    bf16x8 xf[4];
#pragma unroll
    for (int kb = 0; kb < 4; ++kb) {
        const float* p = v0 + (size_t)rc * CH + kb * 32 + kq * 8;
        float4 a = *(const float4*)p;
        float4 bq = *(const float4*)(p + 4);
        union { bf16x8 v; unsigned int u[4]; } r;
        r.u[0] = (unsigned)f2bf(a.x) | ((unsigned)f2bf(a.y) << 16);
        r.u[1] = (unsigned)f2bf(a.z) | ((unsigned)f2bf(a.w) << 16);
        r.u[2] = (unsigned)f2bf(bq.x) | ((unsigned)f2bf(bq.y) << 16);
        r.u[3] = (unsigned)f2bf(bq.z) | ((unsigned)f2bf(bq.w) << 16);
        xf[kb] = r.v;
    }

    f32x4 acc[8];
#pragma unroll
    for (int ct = 0; ct < 8; ++ct) acc[ct] = (f32x4){0.f, 0.f, 0.f, 0.f};
#pragma unroll 2
    for (int ct = 0; ct < 8; ++ct)
#pragma unroll
        for (int kb = 0; kb < 4; ++kb) {
            bf16x8 wf = *(const bf16x8*)&Wp[((ct * 4 + kb) * 64 + l) * 8];
            acc[ct] = __builtin_amdgcn_mfma_f32_16x16x32_bf16(wf, xf[kb], acc[ct], 0, 0, 0);
        }

    if (row < NN) {
        unsigned short* yrow = Hb + (size_t)row * CH;
#pragma unroll
        for (int ct = 0; ct < 8; ++ct) {
            int col = ct * 16 + kq * 4;
            uint2 o;
            o.x = (unsigned)f2bf(acc[ct][0]) | ((unsigned)f2bf(acc[ct][1]) << 16);
            o.y = (unsigned)f2bf(acc[ct][2]) | ((unsigned)f2bf(acc[ct][3]) << 16);
            *(uint2*)(yrow + col) = o;
        }
    }
}

// ---- lean gather: x = relu(agg(h1) + b1), bf16 out. No LDS, 1 node/16-lane group ----
__global__ __launch_bounds__(256) void gather_relu(const uint4* __restrict__ H128,
                                                   const int* __restrict__ cnt,
                                                   const unsigned short* __restrict__ slots,
                                                   const float* __restrict__ bias,
                                                   unsigned short* __restrict__ Xb1) {
    int tid = threadIdx.x;
    int g = tid >> 4, t = tid & 15;
    int node = blockIdx.x * 16 + g;
    if (node >= NN) return;
    int d = min(cnt[node], CAP);
    const unsigned short* sl = slots + (size_t)node * CAP;
    int last = d - 1;

    float acc[8];
#pragma unroll
    for (int k = 0; k < 8; ++k) acc[k] = 0.f;

    for (int i = 0; i < d; i += 8) {
        int e0 = sl[i];
        int e1 = sl[min(i + 1, last)];
        int e2 = sl[min(i + 2, last)];
        int e3 = sl[min(i + 3, last)];
        int e4 = sl[min(i + 4, last)];
        int e5 = sl[min(i + 5, last)];
        int e6 = sl[min(i + 6, last)];
        int e7 = sl[min(i + 7, last)];
        float m1 = (i + 1 <= last) ? 1.f : 0.f;
        float m2 = (i + 2 <= last) ? 1.f : 0.f;
        float m3 = (i + 3 <= last) ? 1.f : 0.f;
        float m4 = (i + 4 <= last) ? 1.f : 0.f;
        float m5 = (i + 5 <= last) ? 1.f : 0.f;
        float m6 = (i + 6 <= last) ? 1.f : 0.f;
        float m7 = (i + 7 <= last) ? 1.f : 0.f;
        uint4 v0 = H128[(size_t)e0 * 16 + t];
        uint4 v1 = H128[(size_t)e1 * 16 + t];
        uint4 v2 = H128[(size_t)e2 * 16 + t];
        uint4 v3 = H128[(size_t)e3 * 16 + t];
        uint4 v4 = H128[(size_t)e4 * 16 + t];
        uint4 v5 = H128[(size_t)e5 * 16 + t];
        uint4 v6 = H128[(size_t)e6 * 16 + t];
        uint4 v7 = H128[(size_t)e7 * 16 + t];
        acc[0] += bflo(v0.x); acc[1] += bfhi(v0.x);
        acc[2] += bflo(v0.y); acc[3] += bfhi(v0.y);
        acc[4] += bflo(v0.z); acc[5] += bfhi(v0.z);
        acc[6] += bflo(v0.w); acc[7] += bfhi(v0.w);
        acc[0] = fmaf(m1, bflo(v1.x), acc[0]); acc[1] = fmaf(m1, bfhi(v1.x), acc[1]);
        acc[2] = fmaf(m1, bflo(v1.y), acc[2]); acc[3] = fmaf(m1, bfhi(v1.y), acc[3]);
        acc[4] = fmaf(m1, bflo(v1.z), acc[4]); acc[5] = fmaf(m1, bfhi(v1.z), acc[5]);
        acc[6] = fmaf(m1, bflo(v1.w), acc[6]); acc[7] = fmaf(m1, bfhi(v1.w), acc[7]);
        acc[0] = fmaf(m2, bflo(v2.x), acc[0]); acc[1] = fmaf(m2, bfhi(v2.x), acc[1]);
        acc[2] = fmaf(m2, bflo(v2.y), acc[2]); acc[3] = fmaf(m2, bfhi(v2.y), acc[3]);
        acc[4] = fmaf(m2, bflo(v2.z), acc[4]); acc[5] = fmaf(m2, bfhi(v2.z), acc[5]);
        acc[6] = fmaf(m2, bflo(v2.w), acc[6]); acc[7] = fmaf(m2, bfhi(v2.w), acc[7]);
        acc[0] = fmaf(m3, bflo(v3.x), acc[0]); acc[1] = fmaf(m3, bfhi(v3.x), acc[1]);
        acc[2] = fmaf(m3, bflo(v3.y), acc[2]); acc[3] = fmaf(m3, bfhi(v3.y), acc[3]);
        acc[4] = fmaf(m3, bflo(v3.z), acc[4]); acc[5] = fmaf(m3, bfhi(v3.z), acc[5]);
        acc[6] = fmaf(m3, bflo(v3.w), acc[6]); acc[7] = fmaf(m3, bfhi(v3.w), acc[7]);
        acc[0] = fmaf(m4, bflo(v4.x), acc[0]); acc[1] = fmaf(m4, bfhi(v4.x), acc[1]);
        acc[2] = fmaf(m4, bflo(v4.y), acc[2]); acc[3] = fmaf(m4, bfhi(v4.y), acc[3]);
        acc[4] = fmaf(m4, bflo(v4.z), acc[4]); acc[5] = fmaf(m4, bfhi(v4.z), acc[5]);
        acc[6] = fmaf(m4, bflo(v4.w), acc[6]); acc[7] = fmaf(m4, bfhi(v4.w), acc[7]);
        acc[0] = fmaf(m5, bflo(v5.x), acc[0]); acc[1] = fmaf(m5, bfhi(v5.x), acc[1]);
        acc[2] = fmaf(m5, bflo(v5.y), acc[2]); acc[3] = fmaf(m5, bfhi(v5.y), acc[3]);
        acc[4] = fmaf(m5, bflo(v5.z), acc[4]); acc[5] = fmaf(m5, bfhi(v5.z), acc[5]);
        acc[6] = fmaf(m5, bflo(v5.w), acc[6]); acc[7] = fmaf(m5, bfhi(v5.w), acc[7]);
        acc[0] = fmaf(m6, bflo(v6.x), acc[0]); acc[1] = fmaf(m6, bfhi(v6.x), acc[1]);
        acc[2] = fmaf(m6, bflo(v6.y), acc[2]); acc[3] = fmaf(m6, bfhi(v6.y), acc[3]);
        acc[4] = fmaf(m6, bflo(v6.z), acc[4]); acc[5] = fmaf(m6, bfhi(v6.z), acc[5]);
        acc[6] = fmaf(m6, bflo(v6.w), acc[6]); acc[7] = fmaf(m6, bfhi(v6.w), acc[7]);
        acc[0] = fmaf(m7, bflo(v7.x), acc[0]); acc[1] = fmaf(m7, bfhi(v7.x), acc[1]);
        acc[2] = fmaf(m7, bflo(v7.y), acc[2]); acc[3] = fmaf(m7, bfhi(v7.y), acc[3]);
        acc[4] = fmaf(m7, bflo(v7.z), acc[4]); acc[5] = fmaf(m7, bfhi(v7.z), acc[5]);
        acc[6] = fmaf(m7, bflo(v7.w), acc[6]); acc[7] = fmaf(m7, bfhi(v7.w), acc[7]);
    }

    float4 bA = *(const float4*)&bias[t * 8];
    float4 bB = *(const float4*)&bias[t * 8 + 4];
    acc[0] += bA.x; acc[1] += bA.y; acc[2] += bA.z; acc[3] += bA.w;
    acc[4] += bB.x; acc[5] += bB.y; acc[6] += bB.z; acc[7] += bB.w;
#pragma unroll
    for (int k = 0; k < 8; ++k) acc[k] = fmaxf(acc[k], 0.f);

    uint4 o;
    o.x = (unsigned)f2bf(acc[0]) | ((unsigned)f2bf(acc[1]) << 16);
    o.y = (unsigned)f2bf(acc[2]) | ((unsigned)f2bf(acc[3]) << 16);
    o.z = (unsigned)f2bf(acc[4]) | ((unsigned)f2bf(acc[5]) << 16);
    o.w = (unsigned)f2bf(acc[6]) | ((unsigned)f2bf(acc[7]) << 16);
    ((uint4*)Xb1)[(size_t)node * 16 + t] = o;
}

// ---- fused layer 2: out = (agg x) @ W2 + b2, f32 out (R10-proven shape) ----
__global__ __launch_bounds__(256) void ggemm2(const uint4* __restrict__ H128,
                                              const int* __restrict__ cnt,
                                              const unsigned short* __restrict__ slots,
                                              const float* __restrict__ bias,
                                              const unsigned short* __restrict__ Wp,
                                              float* __restrict__ Yf32) {
    __shared__ unsigned short WL[32 * 64 * 8];   // 32 KiB packed W2
    __shared__ unsigned short Xl[64 * XPAD];     // 17 KiB agg-tile
    int tid = threadIdx.x;
#pragma unroll
    for (int i = 0; i < 8; ++i)
        ((uint4*)WL)[tid + i * 256] = ((const uint4*)Wp)[tid + i * 256];

    int g = tid >> 4, t = tid & 15;
    int base = blockIdx.x * 64;

    for (int j = 0; j < 4; ++j) {
        int nl = g * 4 + j;
        int node = base + nl;
        float acc[8];
#pragma unroll
        for (int k = 0; k < 8; ++k) acc[k] = 0.f;
        if (node < NN) {
            int d = min(cnt[node], CAP);
            const unsigned short* sl = slots + (size_t)node * CAP;
            int last = d - 1;
            for (int i = 0; i < d; i += 8) {
                int e0 = sl[i];
                int e1 = sl[min(i + 1, last)];
                int e2 = sl[min(i + 2, last)];
                int e3 = sl[min(i + 3, last)];
                int e4 = sl[min(i + 4, last)];
                int e5 = sl[min(i + 5, last)];
                int e6 = sl[min(i + 6, last)];
                int e7 = sl[min(i + 7, last)];
                float m1 = (i + 1 <= last) ? 1.f : 0.f;
                float m2 = (i + 2 <= last) ? 1.f : 0.f;
                float m3 = (i + 3 <= last) ? 1.f : 0.f;
                float m4 = (i + 4 <= last) ? 1.f : 0.f;
                float m5 = (i + 5 <= last) ? 1.f : 0.f;
                float m6 = (i + 6 <= last) ? 1.f : 0.f;
                float m7 = (i + 7 <= last) ? 1.f : 0.f;
                uint4 v0 = H128[(size_t)e0 * 16 + t];
                uint4 v1 = H128[(size_t)e1 * 16 + t];
                uint4 v2 = H128[(size_t)e2 * 16 + t];
                uint4 v3 = H128[(size_t)e3 * 16 + t];
                uint4 v4 = H128[(size_t)e4 * 16 + t];
                uint4 v5 = H128[(size_t)e5 * 16 + t];
                uint4 v6 = H128[(size_t)e6 * 16 + t];
                uint4 v7 = H128[(size_t)e7 * 16 + t];
                acc[0] += bflo(v0.x); acc[1] += bfhi(v0.x);
                acc[2] += bflo(v0.y); acc[3] += bfhi(v0.y);
                acc[4] += bflo(v0.z); acc[5] += bfhi(v0.z);
                acc[6] += bflo(v0.w); acc[7] += bfhi(v0.w);
                acc[0] = fmaf(m1, bflo(v1.x), acc[0]); acc[1] = fmaf(m1, bfhi(v1.x), acc[1]);
                acc[2] = fmaf(m1, bflo(v1.y), acc[2]); acc[3] = fmaf(m1, bfhi(v1.y), acc[3]);
                acc[4] = fmaf(m1, bflo(v1.z), acc[4]); acc[5] = fmaf(m1, bfhi(v1.z), acc[5]);
                acc[6] = fmaf(m1, bflo(v1.w), acc[6]); acc[7] = fmaf(m1, bfhi(v1.w), acc[7]);
                acc[0] = fmaf(m2, bflo(v2.x), acc[0]); acc[1] = fmaf(m2, bfhi(v2.x), acc[1]);
                acc[2] = fmaf(m2, bflo(v2.y), acc[2]); acc[3] = fmaf(m2, bfhi(v2.y), acc[3]);
                acc[4] = fmaf(m2, bflo(v2.z), acc[4]); acc[5] = fmaf(m2, bfhi(v2.z), acc[5]);
                acc[6] = fmaf(m2, bflo(v2.w), acc[6]); acc[7] = fmaf(m2, bfhi(v2.w), acc[7]);
                acc[0] = fmaf(m3, bflo(v3.x), acc[0]); acc[1] = fmaf(m3, bfhi(v3.x), acc[1]);
                acc[2] = fmaf(m3, bflo(v3.y), acc[2]); acc[3] = fmaf(m3, bfhi(v3.y), acc[3]);
                acc[4] = fmaf(m3, bflo(v3.z), acc[4]); acc[5] = fmaf(m3, bfhi(v3.z), acc[5]);
                acc[6] = fmaf(m3, bflo(v3.w), acc[6]); acc[7] = fmaf(m3, bfhi(v3.w), acc[7]);
                acc[0] = fmaf(m4, bflo(v4.x), acc[0]); acc[1] = fmaf(m4, bfhi(v4.x), acc[1]);
                acc[2] = fmaf(m4, bflo(v4.y), acc[2]); acc[3] = fmaf(m4, bfhi(v4.y), acc[3]);
                acc[4] = fmaf(m4, bflo(v4.z), acc[4]); acc[5] = fmaf(m4, bfhi(v4.z), acc[5]);
                acc[6] = fmaf(m4, bflo(v4.w), acc[6]); acc[7] = fmaf(m4, bfhi(v4.w), acc[7]);
                acc[0] = fmaf(m5, bflo(v5.x), acc[0]); acc[1] = fmaf(m5, bfhi(v5.x), acc[1]);
                acc[2] = fmaf(m5, bflo(v5.y), acc[2]); acc[3] = fmaf(m5, bfhi(v5.y), acc[3]);
                acc[4] = fmaf(m5, bflo(v5.z), acc[4]); acc[5] = fmaf(m5, bfhi(v5.z), acc[5]);
                acc[6] = fmaf(m5, bflo(v5.w), acc[6]); acc[7] = fmaf(m5, bfhi(v5.w), acc[7]);
                acc[0] = fmaf(m6, bflo(v6.x), acc[0]); acc[1] = fmaf(m6, bfhi(v6.x), acc[1]);
                acc[2] = fmaf(m6, bflo(v6.y), acc[2]); acc[3] = fmaf(m6, bfhi(v6.y), acc[3]);
                acc[4] = fmaf(m6, bflo(v6.z), acc[4]); acc[5] = fmaf(m6, bfhi(v6.z), acc[5]);
                acc[6] = fmaf(m6, bflo(v6.w), acc[6]); acc[7] = fmaf(m6, bfhi(v6.w), acc[7]);
                acc[0] = fmaf(m7, bflo(v7.x), acc[0]); acc[1] = fmaf(m7, bfhi(v7.x), acc[1]);
                acc[2] = fmaf(m7, bflo(v7.y), acc[2]); acc[3] = fmaf(m7, bfhi(v7.y), acc[3]);
                acc[4] = fmaf(m7, bflo(v7.z), acc[4]); acc[5] = fmaf(m7, bfhi(v7.z), acc[5]);
                acc[6] = fmaf(m7, bflo(v7.w), acc[6]); acc[7] = fmaf(m7, bfhi(v7.w), acc[7]);
            }
        }
        uint4 o;
        o.x = (unsigned)f2bf(acc[0]) | ((unsigned)f2bf(acc[1]) << 16);
        o.y = (unsigned)f2bf(acc[2]) | ((unsigned)f2bf(acc[3]) << 16);
        o.z = (unsigned)f2bf(acc[4]) | ((unsigned)f2bf(acc[5]) << 16);
        o.w = (unsigned)f2bf(acc[6]) | ((unsigned)f2bf(acc[7]) << 16);
        *(uint4*)&Xl[nl * XPAD + t * 8] = o;
    }
    __syncthreads();

    // Phase B: out = aggX @ W2 + b2 (f32 from accumulator)
    int w = tid >> 6, l = tid & 63;
    int rowl = w * 16 + (l & 15);
    int kq = l >> 4;
    bf16x8 xf[4];
#pragma unroll
    for (int kb = 0; kb < 4; ++kb)
        xf[kb] = *(const bf16x8*)&Xl[rowl * XPAD + kb * 32 + kq * 8];

    f32x4 acq[8];
#pragma unroll
    for (int ct = 0; ct < 8; ++ct) acq[ct] = (f32x4){0.f, 0.f, 0.f, 0.f};
#pragma unroll
    for (int ct = 0; ct < 8; ++ct)
#pragma unroll
        for (int kb = 0; kb < 4; ++kb) {
            bf16x8 wf = *(const bf16x8*)&WL[((ct * 4 + kb) * 64 + l) * 8];
            acq[ct] = __builtin_amdgcn_mfma_f32_16x16x32_bf16(wf, xf[kb], acq[ct], 0, 0, 0);
        }

    int row = base + rowl;
    if (row < NN) {
#pragma unroll
        for (int ct = 0; ct < 8; ++ct) {
            int col = ct * 16 + kq * 4;
            float4 bv = *(const float4*)&bias[col];
            *(float4*)&Yf32[(size_t)row * CH + col] =
                make_float4(acq[ct][0] + bv.x, acq[ct][1] + bv.y,
                            acq[ct][2] + bv.z, acq[ct][3] + bv.w);
        }
    }
}

extern "C" void kernel_launch(void* const* d_in, const int* in_sizes, int n_in,
                              void* d_out, int out_size, void* d_ws, size_t ws_size,
                              hipStream_t stream) {
    const float* v0 = (const float*)d_in[0];
    const int* edge = (const int*)d_in[1];   // [2, NE]: row0 = src, row1 = dst
    const float* W1 = (const float*)d_in[2];
    const float* b1 = (const float*)d_in[3];
    const float* W2 = (const float*)d_in[4];
    const float* b2 = (const float*)d_in[5];
    float* out = (float*)d_out;

    const int* srcIdx = edge;
    const int* dstIdx = edge + NE;

    // workspace layout
    unsigned short* Hb    = (unsigned short*)d_ws;    // [NN*CH] bf16 h1 = v0@W1
    unsigned short* Xb1   = Hb + (size_t)NN * CH;     // [NN*CH] bf16 x (layer-1 out)
    unsigned short* Wp    = Xb1 + (size_t)NN * CH;    // [2*16384] packed W1,W2
    int* cnt              = (int*)(Wp + 2 * 16384);   // [NN]
    unsigned short* slots = (unsigned short*)(cnt + NN); // [NN*CAP] ushort src ids

    // K0: zero degree counters + pack weights
    prep<<<65, 256, 0, stream>>>((uint4*)cnt, W1, W2, Wp);

    // K1: h1 = v0 @ W1 (blocks 0..781, no LDS)  ||  bin edges (rest, no LDS)
    fill_gemm1<<<G1B + FILLB, 256, 0, stream>>>(v0, Wp, Hb, srcIdx, dstIdx, cnt, slots);

    // K2: x = relu(agg(h1) + b1)  (lean, high-occupancy)
    gather_relu<<<(NN + 15) / 16, 256, 0, stream>>>((const uint4*)Hb, cnt, slots, b1, Xb1);

    // K3: out = (agg x) @ W2 + b2  (fused, f32 out)
    ggemm2<<<(NN + 63) / 64, 256, 0, stream>>>((const uint4*)Xb1, cnt, slots, b2,
                                               Wp + 16384, out);
}

// Round 14
// 110.546 us; speedup vs baseline: 1.1017x; 1.0681x over previous
//
#include <hip/hip_runtime.h>

#define NN 50000
#define NE 640000
#define CH 128
#define CAP 64                          // slots per node; P(deg>=64)~e^-61 for Poisson(12.8)
#define FILLB ((NE + 255) / 256)        // 2500 edge chunks
#define NPART 8                         // dst partitions (== XCDs)
#define PSZ (NN / NPART)                // 6250 nodes per partition
#define XPAD 136                        // LDS x-tile pitch (ushorts)

typedef __attribute__((ext_vector_type(8))) short bf16x8;
typedef __attribute__((ext_vector_type(4))) float f32x4;

// f32 -> bf16 (RNE)
__device__ __forceinline__ unsigned short f2bf(float x) {
    unsigned int b = __float_as_uint(x);
    b += 0x7fffu + ((b >> 16) & 1u);
    return (unsigned short)(b >> 16);
}
// bf16 pair (packed in uint) -> f32, free bit-ops
__device__ __forceinline__ float bflo(unsigned int u) { return __uint_as_float(u << 16); }
__device__ __forceinline__ float bfhi(unsigned int u) { return __uint_as_float(u & 0xffff0000u); }

// ---- prep: zero cnt (blocks 0..48) + pack W1,W2 to MFMA frag layout (blocks 49..64) ----
__global__ __launch_bounds__(256) void prep(uint4* __restrict__ cntz,
                                            const float* __restrict__ W1,
                                            const float* __restrict__ W2,
                                            unsigned short* __restrict__ Wp) {
    int b = blockIdx.x;
    if (b < 49) {
        int i = b * 256 + threadIdx.x;          // cnt = 50000 ints = 12500 uint4
        if (i < 12500) cntz[i] = make_uint4(0u, 0u, 0u, 0u);
        return;
    }
    int gid = (b - 49) * 256 + threadIdx.x;     // [0, 4096)
    if (gid >= 4096) return;
    const float* W = (gid < 2048) ? W1 : W2;
    int g = gid & 2047;
    int f = g >> 6, l = g & 63;
    int ct = f >> 2, kb = f & 3;
    int col = ct * 16 + (l & 15);
    int k0 = kb * 32 + (l >> 4) * 8;
    unsigned short t[8];
#pragma unroll
    for (int i = 0; i < 8; ++i) t[i] = f2bf(W[(k0 + i) * CH + col]);
    uint4 v;
    v.x = (unsigned)t[0] | ((unsigned)t[1] << 16);
    v.y = (unsigned)t[2] | ((unsigned)t[3] << 16);
    v.z = (unsigned)t[4] | ((unsigned)t[5] << 16);
    v.w = (unsigned)t[6] | ((unsigned)t[7] << 16);
    ((uint4*)Wp)[gid] = v;
}

// ---- XCD-partitioned edge binning ----
// block b: edge chunk b>>3, handles only dst in partition (b&7)*PSZ .. +PSZ.
// Under round-robin block->XCD mapping all stores to a partition stay in one
// XCD's L2 (800KB slots fit 4MB) -> single writeback. Correct regardless of map.
__global__ __launch_bounds__(256) void fill_xcd(const int* __restrict__ srcIdx,
                                                const int* __restrict__ dstIdx,
                                                int* __restrict__ cnt,
                                                unsigned short* __restrict__ slots) {
    int b = blockIdx.x;
    int part = b & (NPART - 1);
    int e = (b >> 3) * 256 + threadIdx.x;
    if (e >= NE) return;
    int d = dstIdx[e];
    int lo = part * PSZ;
    if (d < lo || d >= lo + PSZ) return;
    int p = atomicAdd(&cnt[d], 1);
    if (p < CAP) slots[(size_t)d * CAP + p] = (unsigned short)srcIdx[e];
}

// ---- gemm1: h1 = v0 @ W1 (f32 in, bf16 MFMA via LDS-staged W, bf16 out) ----
__global__ __launch_bounds__(256) void gemm1(const float* __restrict__ v0,
                                             const unsigned short* __restrict__ Wp,
                                             unsigned short* __restrict__ Yb) {
    __shared__ unsigned short WL[32 * 64 * 8];   // 32 KiB
    int tid = threadIdx.x;
#pragma unroll
    for (int i = 0; i < 8; ++i)
        ((uint4*)WL)[tid + i * 256] = ((const uint4*)Wp)[tid + i * 256];

    int w = tid >> 6, l = tid & 63;
    int row = blockIdx.x * 64 + w * 16 + (l & 15);
    int rc = min(row, NN - 1);
    int kq = l >> 4;

    bf16x8 xf[4];
#pragma unroll
    for (int kb = 0; kb < 4; ++kb) {
        const float* p = v0 + (size_t)rc * CH + kb * 32 + kq * 8;
        float4 a = *(const float4*)p;
        float4 bq = *(const float4*)(p + 4);
        union { bf16x8 v; unsigned int u[4]; } r;
        r.u[0] = (unsigned)f2bf(a.x) | ((unsigned)f2bf(a.y) << 16);
        r.u[1] = (unsigned)f2bf(a.z) | ((unsigned)f2bf(a.w) << 16);
        r.u[2] = (unsigned)f2bf(bq.x) | ((unsigned)f2bf(bq.y) << 16);
        r.u[3] = (unsigned)f2bf(bq.z) | ((unsigned)f2bf(bq.w) << 16);
        xf[kb] = r.v;
    }

    __syncthreads();

    f32x4 acc[8];
#pragma unroll
    for (int ct = 0; ct < 8; ++ct) acc[ct] = (f32x4){0.f, 0.f, 0.f, 0.f};
#pragma unroll
    for (int ct = 0; ct < 8; ++ct)
#pragma unroll
        for (int kb = 0; kb < 4; ++kb) {
            bf16x8 wf = *(const bf16x8*)&WL[((ct * 4 + kb) * 64 + l) * 8];
            acc[ct] = __builtin_amdgcn_mfma_f32_16x16x32_bf16(wf, xf[kb], acc[ct], 0, 0, 0);
        }

    if (row < NN) {
        unsigned short* yrow = Yb + (size_t)row * CH;
#pragma unroll
        for (int ct = 0; ct < 8; ++ct) {
            int col = ct * 16 + kq * 4;
            uint2 o;
            o.x = (unsigned)f2bf(acc[ct][0]) | ((unsigned)f2bf(acc[ct][1]) << 16);
            o.y = (unsigned)f2bf(acc[ct][2]) | ((unsigned)f2bf(acc[ct][3]) << 16);
            *(uint2*)(yrow + col) = o;
        }
    }
}

// ---- lean gather: x = relu(agg(h1) + b1), bf16 out. No LDS, 1 node/16-lane group ----
__global__ __launch_bounds__(256) void gather_relu(const uint4* __restrict__ H128,
                                                   const int* __restrict__ cnt,
                                                   const unsigned short* __restrict__ slots,
                                                   const float* __restrict__ bias,
                                                   unsigned short* __restrict__ Xb1) {
    int tid = threadIdx.x;
    int g = tid >> 4, t = tid & 15;
    int node = blockIdx.x * 16 + g;
    if (node >= NN) return;
    int d = min(cnt[node], CAP);
    const unsigned short* sl = slots + (size_t)node * CAP;
    int last = d - 1;

    float acc[8];
#pragma unroll
    for (int k = 0; k < 8; ++k) acc[k] = 0.f;

    for (int i = 0; i < d; i += 8) {
        int e0 = sl[i];
        int e1 = sl[min(i + 1, last)];
        int e2 = sl[min(i + 2, last)];
        int e3 = sl[min(i + 3, last)];
        int e4 = sl[min(i + 4, last)];
        int e5 = sl[min(i + 5, last)];
        int e6 = sl[min(i + 6, last)];
        int e7 = sl[min(i + 7, last)];
        float m1 = (i + 1 <= last) ? 1.f : 0.f;
        float m2 = (i + 2 <= last) ? 1.f : 0.f;
        float m3 = (i + 3 <= last) ? 1.f : 0.f;
        float m4 = (i + 4 <= last) ? 1.f : 0.f;
        float m5 = (i + 5 <= last) ? 1.f : 0.f;
        float m6 = (i + 6 <= last) ? 1.f : 0.f;
        float m7 = (i + 7 <= last) ? 1.f : 0.f;
        uint4 v0 = H128[(size_t)e0 * 16 + t];
        uint4 v1 = H128[(size_t)e1 * 16 + t];
        uint4 v2 = H128[(size_t)e2 * 16 + t];
        uint4 v3 = H128[(size_t)e3 * 16 + t];
        uint4 v4 = H128[(size_t)e4 * 16 + t];
        uint4 v5 = H128[(size_t)e5 * 16 + t];
        uint4 v6 = H128[(size_t)e6 * 16 + t];
        uint4 v7 = H128[(size_t)e7 * 16 + t];
        acc[0] += bflo(v0.x); acc[1] += bfhi(v0.x);
        acc[2] += bflo(v0.y); acc[3] += bfhi(v0.y);
        acc[4] += bflo(v0.z); acc[5] += bfhi(v0.z);
        acc[6] += bflo(v0.w); acc[7] += bfhi(v0.w);
        acc[0] = fmaf(m1, bflo(v1.x), acc[0]); acc[1] = fmaf(m1, bfhi(v1.x), acc[1]);
        acc[2] = fmaf(m1, bflo(v1.y), acc[2]); acc[3] = fmaf(m1, bfhi(v1.y), acc[3]);
        acc[4] = fmaf(m1, bflo(v1.z), acc[4]); acc[5] = fmaf(m1, bfhi(v1.z), acc[5]);
        acc[6] = fmaf(m1, bflo(v1.w), acc[6]); acc[7] = fmaf(m1, bfhi(v1.w), acc[7]);
        acc[0] = fmaf(m2, bflo(v2.x), acc[0]); acc[1] = fmaf(m2, bfhi(v2.x), acc[1]);
        acc[2] = fmaf(m2, bflo(v2.y), acc[2]); acc[3] = fmaf(m2, bfhi(v2.y), acc[3]);
        acc[4] = fmaf(m2, bflo(v2.z), acc[4]); acc[5] = fmaf(m2, bfhi(v2.z), acc[5]);
        acc[6] = fmaf(m2, bflo(v2.w), acc[6]); acc[7] = fmaf(m2, bfhi(v2.w), acc[7]);
        acc[0] = fmaf(m3, bflo(v3.x), acc[0]); acc[1] = fmaf(m3, bfhi(v3.x), acc[1]);
        acc[2] = fmaf(m3, bflo(v3.y), acc[2]); acc[3] = fmaf(m3, bfhi(v3.y), acc[3]);
        acc[4] = fmaf(m3, bflo(v3.z), acc[4]); acc[5] = fmaf(m3, bfhi(v3.z), acc[5]);
        acc[6] = fmaf(m3, bflo(v3.w), acc[6]); acc[7] = fmaf(m3, bfhi(v3.w), acc[7]);
        acc[0] = fmaf(m4, bflo(v4.x), acc[0]); acc[1] = fmaf(m4, bfhi(v4.x), acc[1]);
        acc[2] = fmaf(m4, bflo(v4.y), acc[2]); acc[3] = fmaf(m4, bfhi(v4.y), acc[3]);
        acc[4] = fmaf(m4, bflo(v4.z), acc[4]); acc[5] = fmaf(m4, bfhi(v4.z), acc[5]);
        acc[6] = fmaf(m4, bflo(v4.w), acc[6]); acc[7] = fmaf(m4, bfhi(v4.w), acc[7]);
        acc[0] = fmaf(m5, bflo(v5.x), acc[0]); acc[1] = fmaf(m5, bfhi(v5.x), acc[1]);
        acc[2] = fmaf(m5, bflo(v5.y), acc[2]); acc[3] = fmaf(m5, bfhi(v5.y), acc[3]);
        acc[4] = fmaf(m5, bflo(v5.z), acc[4]); acc[5] = fmaf(m5, bfhi(v5.z), acc[5]);
        acc[6] = fmaf(m5, bflo(v5.w), acc[6]); acc[7] = fmaf(m5, bfhi(v5.w), acc[7]);
        acc[0] = fmaf(m6, bflo(v6.x), acc[0]); acc[1] = fmaf(m6, bfhi(v6.x), acc[1]);
        acc[2] = fmaf(m6, bflo(v6.y), acc[2]); acc[3] = fmaf(m6, bfhi(v6.y), acc[3]);
        acc[4] = fmaf(m6, bflo(v6.z), acc[4]); acc[5] = fmaf(m6, bfhi(v6.z), acc[5]);
        acc[6] = fmaf(m6, bflo(v6.w), acc[6]); acc[7] = fmaf(m6, bfhi(v6.w), acc[7]);
        acc[0] = fmaf(m7, bflo(v7.x), acc[0]); acc[1] = fmaf(m7, bfhi(v7.x), acc[1]);
        acc[2] = fmaf(m7, bflo(v7.y), acc[2]); acc[3] = fmaf(m7, bfhi(v7.y), acc[3]);
        acc[4] = fmaf(m7, bflo(v7.z), acc[4]); acc[5] = fmaf(m7, bfhi(v7.z), acc[5]);
        acc[6] = fmaf(m7, bflo(v7.w), acc[6]); acc[7] = fmaf(m7, bfhi(v7.w), acc[7]);
    }

    float4 bA = *(const float4*)&bias[t * 8];
    float4 bB = *(const float4*)&bias[t * 8 + 4];
    acc[0] += bA.x; acc[1] += bA.y; acc[2] += bA.z; acc[3] += bA.w;
    acc[4] += bB.x; acc[5] += bB.y; acc[6] += bB.z; acc[7] += bB.w;
#pragma unroll
    for (int k = 0; k < 8; ++k) acc[k] = fmaxf(acc[k], 0.f);

    uint4 o;
    o.x = (unsigned)f2bf(acc[0]) | ((unsigned)f2bf(acc[1]) << 16);
    o.y = (unsigned)f2bf(acc[2]) | ((unsigned)f2bf(acc[3]) << 16);
    o.z = (unsigned)f2bf(acc[4]) | ((unsigned)f2bf(acc[5]) << 16);
    o.w = (unsigned)f2bf(acc[6]) | ((unsigned)f2bf(acc[7]) << 16);
    ((uint4*)Xb1)[(size_t)node * 16 + t] = o;
}

// ---- fused layer 2: out = (agg x) @ W2 + b2, f32 out ----
__global__ __launch_bounds__(256) void ggemm2(const uint4* __restrict__ H128,
                                              const int* __restrict__ cnt,
                                              const unsigned short* __restrict__ slots,
                                              const float* __restrict__ bias,
                                              const unsigned short* __restrict__ Wp,
                                              float* __restrict__ Yf32) {
    __shared__ unsigned short WL[32 * 64 * 8];   // 32 KiB packed W2
    __shared__ unsigned short Xl[64 * XPAD];     // 17 KiB agg-tile
    int tid = threadIdx.x;
#pragma unroll
    for (int i = 0; i < 8; ++i)
        ((uint4*)WL)[tid + i * 256] = ((const uint4*)Wp)[tid + i * 256];

    int g = tid >> 4, t = tid & 15;
    int base = blockIdx.x * 64;

    for (int j = 0; j < 4; ++j) {
        int nl = g * 4 + j;
        int node = base + nl;
        float acc[8];
#pragma unroll
        for (int k = 0; k < 8; ++k) acc[k] = 0.f;
        if (node < NN) {
            int d = min(cnt[node], CAP);
            const unsigned short* sl = slots + (size_t)node * CAP;
            int last = d - 1;
            for (int i = 0; i < d; i += 8) {
                int e0 = sl[i];
                int e1 = sl[min(i + 1, last)];
                int e2 = sl[min(i + 2, last)];
                int e3 = sl[min(i + 3, last)];
                int e4 = sl[min(i + 4, last)];
                int e5 = sl[min(i + 5, last)];
                int e6 = sl[min(i + 6, last)];
                int e7 = sl[min(i + 7, last)];
                float m1 = (i + 1 <= last) ? 1.f : 0.f;
                float m2 = (i + 2 <= last) ? 1.f : 0.f;
                float m3 = (i + 3 <= last) ? 1.f : 0.f;
                float m4 = (i + 4 <= last) ? 1.f : 0.f;
                float m5 = (i + 5 <= last) ? 1.f : 0.f;
                float m6 = (i + 6 <= last) ? 1.f : 0.f;
                float m7 = (i + 7 <= last) ? 1.f : 0.f;
                uint4 v0 = H128[(size_t)e0 * 16 + t];
                uint4 v1 = H128[(size_t)e1 * 16 + t];
                uint4 v2 = H128[(size_t)e2 * 16 + t];
                uint4 v3 = H128[(size_t)e3 * 16 + t];
                uint4 v4 = H128[(size_t)e4 * 16 + t];
                uint4 v5 = H128[(size_t)e5 * 16 + t];
                uint4 v6 = H128[(size_t)e6 * 16 + t];
                uint4 v7 = H128[(size_t)e7 * 16 + t];
                acc[0] += bflo(v0.x); acc[1] += bfhi(v0.x);
                acc[2] += bflo(v0.y); acc[3] += bfhi(v0.y);
                acc[4] += bflo(v0.z); acc[5] += bfhi(v0.z);
                acc[6] += bflo(v0.w); acc[7] += bfhi(v0.w);
                acc[0] = fmaf(m1, bflo(v1.x), acc[0]); acc[1] = fmaf(m1, bfhi(v1.x), acc[1]);
                acc[2] = fmaf(m1, bflo(v1.y), acc[2]); acc[3] = fmaf(m1, bfhi(v1.y), acc[3]);
                acc[4] = fmaf(m1, bflo(v1.z), acc[4]); acc[5] = fmaf(m1, bfhi(v1.z), acc[5]);
                acc[6] = fmaf(m1, bflo(v1.w), acc[6]); acc[7] = fmaf(m1, bfhi(v1.w), acc[7]);
                acc[0] = fmaf(m2, bflo(v2.x), acc[0]); acc[1] = fmaf(m2, bfhi(v2.x), acc[1]);
                acc[2] = fmaf(m2, bflo(v2.y), acc[2]); acc[3] = fmaf(m2, bfhi(v2.y), acc[3]);
                acc[4] = fmaf(m2, bflo(v2.z), acc[4]); acc[5] = fmaf(m2, bfhi(v2.z), acc[5]);
                acc[6] = fmaf(m2, bflo(v2.w), acc[6]); acc[7] = fmaf(m2, bfhi(v2.w), acc[7]);
                acc[0] = fmaf(m3, bflo(v3.x), acc[0]); acc[1] = fmaf(m3, bfhi(v3.x), acc[1]);
                acc[2] = fmaf(m3, bflo(v3.y), acc[2]); acc[3] = fmaf(m3, bfhi(v3.y), acc[3]);
                acc[4] = fmaf(m3, bflo(v3.z), acc[4]); acc[5] = fmaf(m3, bfhi(v3.z), acc[5]);
                acc[6] = fmaf(m3, bflo(v3.w), acc[6]); acc[7] = fmaf(m3, bfhi(v3.w), acc[7]);
                acc[0] = fmaf(m4, bflo(v4.x), acc[0]); acc[1] = fmaf(m4, bfhi(v4.x), acc[1]);
                acc[2] = fmaf(m4, bflo(v4.y), acc[2]); acc[3] = fmaf(m4, bfhi(v4.y), acc[3]);
                acc[4] = fmaf(m4, bflo(v4.z), acc[4]); acc[5] = fmaf(m4, bfhi(v4.z), acc[5]);
                acc[6] = fmaf(m4, bflo(v4.w), acc[6]); acc[7] = fmaf(m4, bfhi(v4.w), acc[7]);
                acc[0] = fmaf(m5, bflo(v5.x), acc[0]); acc[1] = fmaf(m5, bfhi(v5.x), acc[1]);
                acc[2] = fmaf(m5, bflo(v5.y), acc[2]); acc[3] = fmaf(m5, bfhi(v5.y), acc[3]);
                acc[4] = fmaf(m5, bflo(v5.z), acc[4]); acc[5] = fmaf(m5, bfhi(v5.z), acc[5]);
                acc[6] = fmaf(m5, bflo(v5.w), acc[6]); acc[7] = fmaf(m5, bfhi(v5.w), acc[7]);
                acc[0] = fmaf(m6, bflo(v6.x), acc[0]); acc[1] = fmaf(m6, bfhi(v6.x), acc[1]);
                acc[2] = fmaf(m6, bflo(v6.y), acc[2]); acc[3] = fmaf(m6, bfhi(v6.y), acc[3]);
                acc[4] = fmaf(m6, bflo(v6.z), acc[4]); acc[5] = fmaf(m6, bfhi(v6.z), acc[5]);
                acc[6] = fmaf(m6, bflo(v6.w), acc[6]); acc[7] = fmaf(m6, bfhi(v6.w), acc[7]);
                acc[0] = fmaf(m7, bflo(v7.x), acc[0]); acc[1] = fmaf(m7, bfhi(v7.x), acc[1]);
                acc[2] = fmaf(m7, bflo(v7.y), acc[2]); acc[3] = fmaf(m7, bfhi(v7.y), acc[3]);
                acc[4] = fmaf(m7, bflo(v7.z), acc[4]); acc[5] = fmaf(m7, bfhi(v7.z), acc[5]);
                acc[6] = fmaf(m7, bflo(v7.w), acc[6]); acc[7] = fmaf(m7, bfhi(v7.w), acc[7]);
            }
        }
        uint4 o;
        o.x = (unsigned)f2bf(acc[0]) | ((unsigned)f2bf(acc[1]) << 16);
        o.y = (unsigned)f2bf(acc[2]) | ((unsigned)f2bf(acc[3]) << 16);
        o.z = (unsigned)f2bf(acc[4]) | ((unsigned)f2bf(acc[5]) << 16);
        o.w = (unsigned)f2bf(acc[6]) | ((unsigned)f2bf(acc[7]) << 16);
        *(uint4*)&Xl[nl * XPAD + t * 8] = o;
    }
    __syncthreads();

    // Phase B: out = aggX @ W2 + b2 (f32 from accumulator)
    int w = tid >> 6, l = tid & 63;
    int rowl = w * 16 + (l & 15);
    int kq = l >> 4;
    bf16x8 xf[4];
#pragma unroll
    for (int kb = 0; kb < 4; ++kb)
        xf[kb] = *(const bf16x8*)&Xl[rowl * XPAD + kb * 32 + kq * 8];

    f32x4 acq[8];
#pragma unroll
    for (int ct = 0; ct < 8; ++ct) acq[ct] = (f32x4){0.f, 0.f, 0.f, 0.f};
#pragma unroll
    for (int ct = 0; ct < 8; ++ct)
#pragma unroll
        for (int kb = 0; kb < 4; ++kb) {
            bf16x8 wf = *(const bf16x8*)&WL[((ct * 4 + kb) * 64 + l) * 8];
            acq[ct] = __builtin_amdgcn_mfma_f32_16x16x32_bf16(wf, xf[kb], acq[ct], 0, 0, 0);
        }

    int row = base + rowl;
    if (row < NN) {
#pragma unroll
        for (int ct = 0; ct < 8; ++ct) {
            int col = ct * 16 + kq * 4;
            float4 bv = *(const float4*)&bias[col];
            *(float4*)&Yf32[(size_t)row * CH + col] =
                make_float4(acq[ct][0] + bv.x, acq[ct][1] + bv.y,
                            acq[ct][2] + bv.z, acq[ct][3] + bv.w);
        }
    }
}

extern "C" void kernel_launch(void* const* d_in, const int* in_sizes, int n_in,
                              void* d_out, int out_size, void* d_ws, size_t ws_size,
                              hipStream_t stream) {
    const float* v0 = (const float*)d_in[0];
    const int* edge = (const int*)d_in[1];   // [2, NE]: row0 = src, row1 = dst
    const float* W1 = (const float*)d_in[2];
    const float* b1 = (const float*)d_in[3];
    const float* W2 = (const float*)d_in[4];
    const float* b2 = (const float*)d_in[5];
    float* out = (float*)d_out;

    const int* srcIdx = edge;
    const int* dstIdx = edge + NE;

    // workspace layout
    unsigned short* Hb    = (unsigned short*)d_ws;    // [NN*CH] bf16 h1 = v0@W1
    unsigned short* Xb1   = Hb + (size_t)NN * CH;     // [NN*CH] bf16 x (layer-1 out)
    unsigned short* Wp    = Xb1 + (size_t)NN * CH;    // [2*16384] packed W1,W2
    int* cnt              = (int*)(Wp + 2 * 16384);   // [NN]
    unsigned short* slots = (unsigned short*)(cnt + NN); // [NN*CAP] ushort src ids

    // K0: zero degree counters + pack weights
    prep<<<65, 256, 0, stream>>>((uint4*)cnt, W1, W2, Wp);

    // K1: XCD-partitioned edge binning (8 partitions x 2500 chunks)
    fill_xcd<<<FILLB * NPART, 256, 0, stream>>>(srcIdx, dstIdx, cnt, slots);

    // K2: h1 = v0 @ W1
    gemm1<<<(NN + 63) / 64, 256, 0, stream>>>(v0, Wp, Hb);

    // K3: x = relu(agg(h1) + b1)
    gather_relu<<<(NN + 15) / 16, 256, 0, stream>>>((const uint4*)Hb, cnt, slots, b1, Xb1);

    // K4: out = (agg x) @ W2 + b2
    ggemm2<<<(NN + 63) / 64, 256, 0, stream>>>((const uint4*)Xb1, cnt, slots, b2,
                                               Wp + 16384, out);
}

// Round 15
// 104.562 us; speedup vs baseline: 1.1648x; 1.0572x over previous
//
#include <hip/hip_runtime.h>

#define NN 50000
#define NE 640000
#define CH 128
#define CAP 64                          // slots per node; P(deg>=64)~e^-61 for Poisson(12.8)
#define G1B ((NN + 63) / 64)            // 782 gemm1 blocks
#define FILLB ((NE + 255) / 256)        // 2500 edge chunks
#define NPART 8                         // dst partitions (== XCDs)
#define PSZ (NN / NPART)                // 6250 nodes per partition
#define XPAD 136                        // LDS x-tile pitch (ushorts)

typedef __attribute__((ext_vector_type(8))) short bf16x8;
typedef __attribute__((ext_vector_type(4))) float f32x4;

// f32 -> bf16 (RNE)
__device__ __forceinline__ unsigned short f2bf(float x) {
    unsigned int b = __float_as_uint(x);
    b += 0x7fffu + ((b >> 16) & 1u);
    return (unsigned short)(b >> 16);
}
// bf16 pair (packed in uint) -> f32, free bit-ops
__device__ __forceinline__ float bflo(unsigned int u) { return __uint_as_float(u << 16); }
__device__ __forceinline__ float bfhi(unsigned int u) { return __uint_as_float(u & 0xffff0000u); }

// ---- prep: zero cnt (blocks 0..48) + pack W1,W2 to MFMA frag layout (blocks 49..64) ----
__global__ __launch_bounds__(256) void prep(uint4* __restrict__ cntz,
                                            const float* __restrict__ W1,
                                            const float* __restrict__ W2,
                                            unsigned short* __restrict__ Wp) {
    int b = blockIdx.x;
    if (b < 49) {
        int i = b * 256 + threadIdx.x;          // cnt = 50000 ints = 12500 uint4
        if (i < 12500) cntz[i] = make_uint4(0u, 0u, 0u, 0u);
        return;
    }
    int gid = (b - 49) * 256 + threadIdx.x;     // [0, 4096)
    if (gid >= 4096) return;
    const float* W = (gid < 2048) ? W1 : W2;
    int g = gid & 2047;
    int f = g >> 6, l = g & 63;
    int ct = f >> 2, kb = f & 3;
    int col = ct * 16 + (l & 15);
    int k0 = kb * 32 + (l >> 4) * 8;
    unsigned short t[8];
#pragma unroll
    for (int i = 0; i < 8; ++i) t[i] = f2bf(W[(k0 + i) * CH + col]);
    uint4 v;
    v.x = (unsigned)t[0] | ((unsigned)t[1] << 16);
    v.y = (unsigned)t[2] | ((unsigned)t[3] << 16);
    v.z = (unsigned)t[4] | ((unsigned)t[5] << 16);
    v.w = (unsigned)t[6] | ((unsigned)t[7] << 16);
    ((uint4*)Wp)[gid] = v;
}

// ---- split grid, NO LDS: blocks [0,G1B) gemm1 (W from global); rest XCD-binned fill ----
// fill part = b&7: all blocks of one partition land on one XCD (round-robin map),
// so each partition's 800KB slot region stays in that XCD's L2. Correct for any map.
__global__ __launch_bounds__(256) void fillgemm1(const float* __restrict__ v0,
                                                 const unsigned short* __restrict__ Wp,
                                                 unsigned short* __restrict__ Hb,
                                                 const int* __restrict__ srcIdx,
                                                 const int* __restrict__ dstIdx,
                                                 int* __restrict__ cnt,
                                                 unsigned short* __restrict__ slots) {
    int b = blockIdx.x, tid = threadIdx.x;
    if (b >= G1B) {
        int f = b - G1B;                    // [0, FILLB*8)
        int part = b & (NPART - 1);
        int e = (f >> 3) * 256 + tid;
        if (e >= NE) return;
        int d = dstIdx[e];
        int lo = part * PSZ;
        if (d < lo || d >= lo + PSZ) return;
        int p = atomicAdd(&cnt[d], 1);
        if (p < CAP) slots[(size_t)d * CAP + p] = (unsigned short)srcIdx[e];
        return;
    }
    // gemm1: rows b*64..+63, f32 input, W fragments from global (L2-resident)
    int w = tid >> 6, l = tid & 63;
    int row = b * 64 + w * 16 + (l & 15);
    int rc = min(row, NN - 1);
    int kq = l >> 4;

    bf16x8 xf[4];
#pragma unroll
    for (int kb = 0; kb < 4; ++kb) {
        const float* p = v0 + (size_t)rc * CH + kb * 32 + kq * 8;
        float4 a = *(const float4*)p;
        float4 bq = *(const float4*)(p + 4);
        union { bf16x8 v; unsigned int u[4]; } r;
        r.u[0] = (unsigned)f2bf(a.x) | ((unsigned)f2bf(a.y) << 16);
        r.u[1] = (unsigned)f2bf(a.z) | ((unsigned)f2bf(a.w) << 16);
        r.u[2] = (unsigned)f2bf(bq.x) | ((unsigned)f2bf(bq.y) << 16);
        r.u[3] = (unsigned)f2bf(bq.z) | ((unsigned)f2bf(bq.w) << 16);
        xf[kb] = r.v;
    }

    f32x4 acc[8];
#pragma unroll
    for (int ct = 0; ct < 8; ++ct) acc[ct] = (f32x4){0.f, 0.f, 0.f, 0.f};
#pragma unroll 2
    for (int ct = 0; ct < 8; ++ct)
#pragma unroll
        for (int kb = 0; kb < 4; ++kb) {
            bf16x8 wf = *(const bf16x8*)&Wp[((ct * 4 + kb) * 64 + l) * 8];
            acc[ct] = __builtin_amdgcn_mfma_f32_16x16x32_bf16(wf, xf[kb], acc[ct], 0, 0, 0);
        }

    if (row < NN) {
        unsigned short* yrow = Hb + (size_t)row * CH;
#pragma unroll
        for (int ct = 0; ct < 8; ++ct) {
            int col = ct * 16 + kq * 4;
            uint2 o;
            o.x = (unsigned)f2bf(acc[ct][0]) | ((unsigned)f2bf(acc[ct][1]) << 16);
            o.y = (unsigned)f2bf(acc[ct][2]) | ((unsigned)f2bf(acc[ct][3]) << 16);
            *(uint2*)(yrow + col) = o;
        }
    }
}

// ---- lean gather: x = relu(agg(h1) + b1), bf16 out. No LDS, 1 node/16-lane group ----
__global__ __launch_bounds__(256) void gather_relu(const uint4* __restrict__ H128,
                                                   const int* __restrict__ cnt,
                                                   const unsigned short* __restrict__ slots,
                                                   const float* __restrict__ bias,
                                                   unsigned short* __restrict__ Xb1) {
    int tid = threadIdx.x;
    int g = tid >> 4, t = tid & 15;
    int node = blockIdx.x * 16 + g;
    if (node >= NN) return;
    int d = min(cnt[node], CAP);
    const unsigned short* sl = slots + (size_t)node * CAP;
    int last = d - 1;

    float acc[8];
#pragma unroll
    for (int k = 0; k < 8; ++k) acc[k] = 0.f;

    for (int i = 0; i < d; i += 8) {
        int e0 = sl[i];
        int e1 = sl[min(i + 1, last)];
        int e2 = sl[min(i + 2, last)];
        int e3 = sl[min(i + 3, last)];
        int e4 = sl[min(i + 4, last)];
        int e5 = sl[min(i + 5, last)];
        int e6 = sl[min(i + 6, last)];
        int e7 = sl[min(i + 7, last)];
        float m1 = (i + 1 <= last) ? 1.f : 0.f;
        float m2 = (i + 2 <= last) ? 1.f : 0.f;
        float m3 = (i + 3 <= last) ? 1.f : 0.f;
        float m4 = (i + 4 <= last) ? 1.f : 0.f;
        float m5 = (i + 5 <= last) ? 1.f : 0.f;
        float m6 = (i + 6 <= last) ? 1.f : 0.f;
        float m7 = (i + 7 <= last) ? 1.f : 0.f;
        uint4 v0 = H128[(size_t)e0 * 16 + t];
        uint4 v1 = H128[(size_t)e1 * 16 + t];
        uint4 v2 = H128[(size_t)e2 * 16 + t];
        uint4 v3 = H128[(size_t)e3 * 16 + t];
        uint4 v4 = H128[(size_t)e4 * 16 + t];
        uint4 v5 = H128[(size_t)e5 * 16 + t];
        uint4 v6 = H128[(size_t)e6 * 16 + t];
        uint4 v7 = H128[(size_t)e7 * 16 + t];
        acc[0] += bflo(v0.x); acc[1] += bfhi(v0.x);
        acc[2] += bflo(v0.y); acc[3] += bfhi(v0.y);
        acc[4] += bflo(v0.z); acc[5] += bfhi(v0.z);
        acc[6] += bflo(v0.w); acc[7] += bfhi(v0.w);
        acc[0] = fmaf(m1, bflo(v1.x), acc[0]); acc[1] = fmaf(m1, bfhi(v1.x), acc[1]);
        acc[2] = fmaf(m1, bflo(v1.y), acc[2]); acc[3] = fmaf(m1, bfhi(v1.y), acc[3]);
        acc[4] = fmaf(m1, bflo(v1.z), acc[4]); acc[5] = fmaf(m1, bfhi(v1.z), acc[5]);
        acc[6] = fmaf(m1, bflo(v1.w), acc[6]); acc[7] = fmaf(m1, bfhi(v1.w), acc[7]);
        acc[0] = fmaf(m2, bflo(v2.x), acc[0]); acc[1] = fmaf(m2, bfhi(v2.x), acc[1]);
        acc[2] = fmaf(m2, bflo(v2.y), acc[2]); acc[3] = fmaf(m2, bfhi(v2.y), acc[3]);
        acc[4] = fmaf(m2, bflo(v2.z), acc[4]); acc[5] = fmaf(m2, bfhi(v2.z), acc[5]);
        acc[6] = fmaf(m2, bflo(v2.w), acc[6]); acc[7] = fmaf(m2, bfhi(v2.w), acc[7]);
        acc[0] = fmaf(m3, bflo(v3.x), acc[0]); acc[1] = fmaf(m3, bfhi(v3.x), acc[1]);
        acc[2] = fmaf(m3, bflo(v3.y), acc[2]); acc[3] = fmaf(m3, bfhi(v3.y), acc[3]);
        acc[4] = fmaf(m3, bflo(v3.z), acc[4]); acc[5] = fmaf(m3, bfhi(v3.z), acc[5]);
        acc[6] = fmaf(m3, bflo(v3.w), acc[6]); acc[7] = fmaf(m3, bfhi(v3.w), acc[7]);
        acc[0] = fmaf(m4, bflo(v4.x), acc[0]); acc[1] = fmaf(m4, bfhi(v4.x), acc[1]);
        acc[2] = fmaf(m4, bflo(v4.y), acc[2]); acc[3] = fmaf(m4, bfhi(v4.y), acc[3]);
        acc[4] = fmaf(m4, bflo(v4.z), acc[4]); acc[5] = fmaf(m4, bfhi(v4.z), acc[5]);
        acc[6] = fmaf(m4, bflo(v4.w), acc[6]); acc[7] = fmaf(m4, bfhi(v4.w), acc[7]);
        acc[0] = fmaf(m5, bflo(v5.x), acc[0]); acc[1] = fmaf(m5, bfhi(v5.x), acc[1]);
        acc[2] = fmaf(m5, bflo(v5.y), acc[2]); acc[3] = fmaf(m5, bfhi(v5.y), acc[3]);
        acc[4] = fmaf(m5, bflo(v5.z), acc[4]); acc[5] = fmaf(m5, bfhi(v5.z), acc[5]);
        acc[6] = fmaf(m5, bflo(v5.w), acc[6]); acc[7] = fmaf(m5, bfhi(v5.w), acc[7]);
        acc[0] = fmaf(m6, bflo(v6.x), acc[0]); acc[1] = fmaf(m6, bfhi(v6.x), acc[1]);
        acc[2] = fmaf(m6, bflo(v6.y), acc[2]); acc[3] = fmaf(m6, bfhi(v6.y), acc[3]);
        acc[4] = fmaf(m6, bflo(v6.z), acc[4]); acc[5] = fmaf(m6, bfhi(v6.z), acc[5]);
        acc[6] = fmaf(m6, bflo(v6.w), acc[6]); acc[7] = fmaf(m6, bfhi(v6.w), acc[7]);
        acc[0] = fmaf(m7, bflo(v7.x), acc[0]); acc[1] = fmaf(m7, bfhi(v7.x), acc[1]);
        acc[2] = fmaf(m7, bflo(v7.y), acc[2]); acc[3] = fmaf(m7, bfhi(v7.y), acc[3]);
        acc[4] = fmaf(m7, bflo(v7.z), acc[4]); acc[5] = fmaf(m7, bfhi(v7.z), acc[5]);
        acc[6] = fmaf(m7, bflo(v7.w), acc[6]); acc[7] = fmaf(m7, bfhi(v7.w), acc[7]);
    }

    float4 bA = *(const float4*)&bias[t * 8];
    float4 bB = *(const float4*)&bias[t * 8 + 4];
    acc[0] += bA.x; acc[1] += bA.y; acc[2] += bA.z; acc[3] += bA.w;
    acc[4] += bB.x; acc[5] += bB.y; acc[6] += bB.z; acc[7] += bB.w;
#pragma unroll
    for (int k = 0; k < 8; ++k) acc[k] = fmaxf(acc[k], 0.f);

    uint4 o;
    o.x = (unsigned)f2bf(acc[0]) | ((unsigned)f2bf(acc[1]) << 16);
    o.y = (unsigned)f2bf(acc[2]) | ((unsigned)f2bf(acc[3]) << 16);
    o.z = (unsigned)f2bf(acc[4]) | ((unsigned)f2bf(acc[5]) << 16);
    o.w = (unsigned)f2bf(acc[6]) | ((unsigned)f2bf(acc[7]) << 16);
    ((uint4*)Xb1)[(size_t)node * 16 + t] = o;
}

// ---- fused layer 2: out = (agg x) @ W2 + b2, f32 out. No W-LDS (occupancy) ----
__global__ __launch_bounds__(256) void ggemm2(const uint4* __restrict__ H128,
                                              const int* __restrict__ cnt,
                                              const unsigned short* __restrict__ slots,
                                              const float* __restrict__ bias,
                                              const unsigned short* __restrict__ Wp,
                                              float* __restrict__ Yf32) {
    __shared__ unsigned short Xl[64 * XPAD];     // 17 KiB agg-tile (only LDS)
    int tid = threadIdx.x;
    int g = tid >> 4, t = tid & 15;
    int base = blockIdx.x * 64;

    for (int j = 0; j < 4; ++j) {
        int nl = g * 4 + j;
        int node = base + nl;
        float acc[8];
#pragma unroll
        for (int k = 0; k < 8; ++k) acc[k] = 0.f;
        if (node < NN) {
            int d = min(cnt[node], CAP);
            const unsigned short* sl = slots + (size_t)node * CAP;
            int last = d - 1;
            for (int i = 0; i < d; i += 8) {
                int e0 = sl[i];
                int e1 = sl[min(i + 1, last)];
                int e2 = sl[min(i + 2, last)];
                int e3 = sl[min(i + 3, last)];
                int e4 = sl[min(i + 4, last)];
                int e5 = sl[min(i + 5, last)];
                int e6 = sl[min(i + 6, last)];
                int e7 = sl[min(i + 7, last)];
                float m1 = (i + 1 <= last) ? 1.f : 0.f;
                float m2 = (i + 2 <= last) ? 1.f : 0.f;
                float m3 = (i + 3 <= last) ? 1.f : 0.f;
                float m4 = (i + 4 <= last) ? 1.f : 0.f;
                float m5 = (i + 5 <= last) ? 1.f : 0.f;
                float m6 = (i + 6 <= last) ? 1.f : 0.f;
                float m7 = (i + 7 <= last) ? 1.f : 0.f;
                uint4 v0 = H128[(size_t)e0 * 16 + t];
                uint4 v1 = H128[(size_t)e1 * 16 + t];
                uint4 v2 = H128[(size_t)e2 * 16 + t];
                uint4 v3 = H128[(size_t)e3 * 16 + t];
                uint4 v4 = H128[(size_t)e4 * 16 + t];
                uint4 v5 = H128[(size_t)e5 * 16 + t];
                uint4 v6 = H128[(size_t)e6 * 16 + t];
                uint4 v7 = H128[(size_t)e7 * 16 + t];
                acc[0] += bflo(v0.x); acc[1] += bfhi(v0.x);
                acc[2] += bflo(v0.y); acc[3] += bfhi(v0.y);
                acc[4] += bflo(v0.z); acc[5] += bfhi(v0.z);
                acc[6] += bflo(v0.w); acc[7] += bfhi(v0.w);
                acc[0] = fmaf(m1, bflo(v1.x), acc[0]); acc[1] = fmaf(m1, bfhi(v1.x), acc[1]);
                acc[2] = fmaf(m1, bflo(v1.y), acc[2]); acc[3] = fmaf(m1, bfhi(v1.y), acc[3]);
                acc[4] = fmaf(m1, bflo(v1.z), acc[4]); acc[5] = fmaf(m1, bfhi(v1.z), acc[5]);
                acc[6] = fmaf(m1, bflo(v1.w), acc[6]); acc[7] = fmaf(m1, bfhi(v1.w), acc[7]);
                acc[0] = fmaf(m2, bflo(v2.x), acc[0]); acc[1] = fmaf(m2, bfhi(v2.x), acc[1]);
                acc[2] = fmaf(m2, bflo(v2.y), acc[2]); acc[3] = fmaf(m2, bfhi(v2.y), acc[3]);
                acc[4] = fmaf(m2, bflo(v2.z), acc[4]); acc[5] = fmaf(m2, bfhi(v2.z), acc[5]);
                acc[6] = fmaf(m2, bflo(v2.w), acc[6]); acc[7] = fmaf(m2, bfhi(v2.w), acc[7]);
                acc[0] = fmaf(m3, bflo(v3.x), acc[0]); acc[1] = fmaf(m3, bfhi(v3.x), acc[1]);
                acc[2] = fmaf(m3, bflo(v3.y), acc[2]); acc[3] = fmaf(m3, bfhi(v3.y), acc[3]);
                acc[4] = fmaf(m3, bflo(v3.z), acc[4]); acc[5] = fmaf(m3, bfhi(v3.z), acc[5]);
                acc[6] = fmaf(m3, bflo(v3.w), acc[6]); acc[7] = fmaf(m3, bfhi(v3.w), acc[7]);
                acc[0] = fmaf(m4, bflo(v4.x), acc[0]); acc[1] = fmaf(m4, bfhi(v4.x), acc[1]);
                acc[2] = fmaf(m4, bflo(v4.y), acc[2]); acc[3] = fmaf(m4, bfhi(v4.y), acc[3]);
                acc[4] = fmaf(m4, bflo(v4.z), acc[4]); acc[5] = fmaf(m4, bfhi(v4.z), acc[5]);
                acc[6] = fmaf(m4, bflo(v4.w), acc[6]); acc[7] = fmaf(m4, bfhi(v4.w), acc[7]);
                acc[0] = fmaf(m5, bflo(v5.x), acc[0]); acc[1] = fmaf(m5, bfhi(v5.x), acc[1]);
                acc[2] = fmaf(m5, bflo(v5.y), acc[2]); acc[3] = fmaf(m5, bfhi(v5.y), acc[3]);
                acc[4] = fmaf(m5, bflo(v5.z), acc[4]); acc[5] = fmaf(m5, bfhi(v5.z), acc[5]);
                acc[6] = fmaf(m5, bflo(v5.w), acc[6]); acc[7] = fmaf(m5, bfhi(v5.w), acc[7]);
                acc[0] = fmaf(m6, bflo(v6.x), acc[0]); acc[1] = fmaf(m6, bfhi(v6.x), acc[1]);
                acc[2] = fmaf(m6, bflo(v6.y), acc[2]); acc[3] = fmaf(m6, bfhi(v6.y), acc[3]);
                acc[4] = fmaf(m6, bflo(v6.z), acc[4]); acc[5] = fmaf(m6, bfhi(v6.z), acc[5]);
                acc[6] = fmaf(m6, bflo(v6.w), acc[6]); acc[7] = fmaf(m6, bfhi(v6.w), acc[7]);
                acc[0] = fmaf(m7, bflo(v7.x), acc[0]); acc[1] = fmaf(m7, bfhi(v7.x), acc[1]);
                acc[2] = fmaf(m7, bflo(v7.y), acc[2]); acc[3] = fmaf(m7, bfhi(v7.y), acc[3]);
                acc[4] = fmaf(m7, bflo(v7.z), acc[4]); acc[5] = fmaf(m7, bfhi(v7.z), acc[5]);
                acc[6] = fmaf(m7, bflo(v7.w), acc[6]); acc[7] = fmaf(m7, bfhi(v7.w), acc[7]);
            }
        }
        uint4 o;
        o.x = (unsigned)f2bf(acc[0]) | ((unsigned)f2bf(acc[1]) << 16);
        o.y = (unsigned)f2bf(acc[2]) | ((unsigned)f2bf(acc[3]) << 16);
        o.z = (unsigned)f2bf(acc[4]) | ((unsigned)f2bf(acc[5]) << 16);
        o.w = (unsigned)f2bf(acc[6]) | ((unsigned)f2bf(acc[7]) << 16);
        *(uint4*)&Xl[nl * XPAD + t * 8] = o;
    }
    __syncthreads();

    // Phase B: out = aggX @ W2 + b2 (f32 from accumulator); W from global (L2)
    int w = tid >> 6, l = tid & 63;
    int rowl = w * 16 + (l & 15);
    int kq = l >> 4;
    bf16x8 xf[4];
#pragma unroll
    for (int kb = 0; kb < 4; ++kb)
        xf[kb] = *(const bf16x8*)&Xl[rowl * XPAD + kb * 32 + kq * 8];

    f32x4 acq[8];
#pragma unroll
    for (int ct = 0; ct < 8; ++ct) acq[ct] = (f32x4){0.f, 0.f, 0.f, 0.f};
#pragma unroll 2
    for (int ct = 0; ct < 8; ++ct)
#pragma unroll
        for (int kb = 0; kb < 4; ++kb) {
            bf16x8 wf = *(const bf16x8*)&Wp[((ct * 4 + kb) * 64 + l) * 8];
            acq[ct] = __builtin_amdgcn_mfma_f32_16x16x32_bf16(wf, xf[kb], acq[ct], 0, 0, 0);
        }

    int row = base + rowl;
    if (row < NN) {
#pragma unroll
        for (int ct = 0; ct < 8; ++ct) {
            int col = ct * 16 + kq * 4;
            float4 bv = *(const float4*)&bias[col];
            *(float4*)&Yf32[(size_t)row * CH + col] =
                make_float4(acq[ct][0] + bv.x, acq[ct][1] + bv.y,
                            acq[ct][2] + bv.z, acq[ct][3] + bv.w);
        }
    }
}

extern "C" void kernel_launch(void* const* d_in, const int* in_sizes, int n_in,
                              void* d_out, int out_size, void* d_ws, size_t ws_size,
                              hipStream_t stream) {
    const float* v0 = (const float*)d_in[0];
    const int* edge = (const int*)d_in[1];   // [2, NE]: row0 = src, row1 = dst
    const float* W1 = (const float*)d_in[2];
    const float* b1 = (const float*)d_in[3];
    const float* W2 = (const float*)d_in[4];
    const float* b2 = (const float*)d_in[5];
    float* out = (float*)d_out;

    const int* srcIdx = edge;
    const int* dstIdx = edge + NE;

    // workspace layout
    unsigned short* Hb    = (unsigned short*)d_ws;    // [NN*CH] bf16 h1 = v0@W1
    unsigned short* Xb1   = Hb + (size_t)NN * CH;     // [NN*CH] bf16 x (layer-1 out)
    unsigned short* Wp    = Xb1 + (size_t)NN * CH;    // [2*16384] packed W1,W2
    int* cnt              = (int*)(Wp + 2 * 16384);   // [NN]
    unsigned short* slots = (unsigned short*)(cnt + NN); // [NN*CAP] ushort src ids

    // K0: zero degree counters + pack weights
    prep<<<65, 256, 0, stream>>>((uint4*)cnt, W1, W2, Wp);

    // K1: h1 = v0@W1 (blocks 0..781) || XCD-binned edge fill (rest); all LDS-free
    fillgemm1<<<G1B + FILLB * NPART, 256, 0, stream>>>(v0, Wp, Hb,
                                                       srcIdx, dstIdx, cnt, slots);

    // K2: x = relu(agg(h1) + b1)
    gather_relu<<<(NN + 15) / 16, 256, 0, stream>>>((const uint4*)Hb, cnt, slots, b1, Xb1);

    // K3: out = (agg x) @ W2 + b2
    ggemm2<<<(NN + 63) / 64, 256, 0, stream>>>((const uint4*)Xb1, cnt, slots, b2,
                                               Wp + 16384, out);
}